// Round 11
// baseline (132.097 us; speedup 1.0000x reference)
//
#include <hip/hip_runtime.h>
#include <hip/hip_bf16.h>
#include <math.h>

#define B_ 2
#define S_ 4096
#define H_ 8
#define D_ 64
#define W_ 512

#define MASKV -1e30f

typedef float f32x4 __attribute__((ext_vector_type(4)));
typedef short s16x4 __attribute__((ext_vector_type(4)));
typedef short s16x8 __attribute__((ext_vector_type(8)));
typedef unsigned int u32;
typedef __attribute__((address_space(1))) const u32 as1_u32;
typedef __attribute__((address_space(3))) u32 as3_u32;

__device__ inline short f2bf(float f) {
    unsigned u = __builtin_bit_cast(unsigned, f);
    unsigned r = (u + 0x7FFFu + ((u >> 16) & 1u)) >> 16;
    return (short)r;
}
__device__ inline s16x8 pack8(f32x4 a, f32x4 b) {
    s16x8 r;
    r[0]=f2bf(a[0]); r[1]=f2bf(a[1]); r[2]=f2bf(a[2]); r[3]=f2bf(a[3]);
    r[4]=f2bf(b[0]); r[5]=f2bf(b[1]); r[6]=f2bf(b[2]); r[7]=f2bf(b[3]);
    return r;
}
__device__ __forceinline__ void gl_lds16(const void* g, void* l) {
    __builtin_amdgcn_global_load_lds((as1_u32*)(unsigned long long)g,
                                     (as3_u32*)(u32)(unsigned long long)l,
                                     16, 0, 0);
}
// drain ALL outstanding async global->LDS writes of this wave; must precede
// s_barrier so other waves see our staged rows after barrier release.
__device__ __forceinline__ void drain_vmem() {
    asm volatile("s_waitcnt vmcnt(0)" ::: "memory");
}

// ---------------------------------------------------------------------------
// Fused pre-pass (one launch):
//   blocks [0,2304):    xs + prev_k fp32 -> bf16 flat
//   blocks [2304,2432): prev_v -> vbt bf16 [h*64+d][b*4608 + jj]
//   blocks [2432,2624): wt[z*512+n][k] = w_z[k][n] * scale_z, bf16
// ---------------------------------------------------------------------------
__global__ __launch_bounds__(256, 4)
void prep_kernel(const float* __restrict__ xs, const float* __restrict__ pk,
                 const float* __restrict__ pv, const float* __restrict__ wq,
                 const float* __restrict__ wk, const float* __restrict__ wv,
                 short* __restrict__ xsbf, short* __restrict__ pkbf,
                 short* __restrict__ vbt, short* __restrict__ wt)
{
    __shared__ char smem[17408];
    const int bid = blockIdx.x;
    const int tid = threadIdx.x;

    if (bid < 2304) {
        // ---- convert xs + prev_k ----
        size_t i8 = ((size_t)bid * 256 + tid) * 8;
        const float* src; short* dst; size_t off;
        if (i8 < 4194304) { src = xs; dst = xsbf; off = i8; }
        else              { src = pk; dst = pkbf; off = i8 - 4194304; }
        f32x4 a = *(const f32x4*)(src + off);
        f32x4 b = *(const f32x4*)(src + off + 4);
        *(s16x8*)(dst + off) = pack8(a, b);
    } else if (bid < 2432) {
        // ---- prev_v transpose ----
        short (*st)[72] = (short(*)[72])smem;
        const int b2 = bid - 2304;
        const int jt = b2 & 7, h = (b2 >> 3) & 7, b = b2 >> 6;
        const int jj0 = jt * 64;
        {
            int kk = tid >> 2, d0 = (tid & 3) * 16;
            const float* src = pv + (((size_t)(b * 512 + jj0 + kk)) * 8 + h) * 64 + d0;
            f32x4 x0 = *(const f32x4*)(src);
            f32x4 x1 = *(const f32x4*)(src + 4);
            f32x4 x2 = *(const f32x4*)(src + 8);
            f32x4 x3 = *(const f32x4*)(src + 12);
            *(s16x8*)&st[kk][d0]     = pack8(x0, x1);
            *(s16x8*)&st[kk][d0 + 8] = pack8(x2, x3);
        }
        __syncthreads();
        {
            int dd = tid >> 2, k0 = (tid & 3) * 16;
            s16x8 o0, o1;
            #pragma unroll
            for (int t = 0; t < 8; ++t) { o0[t] = st[k0 + t][dd]; o1[t] = st[k0 + 8 + t][dd]; }
            short* dst = vbt + (size_t)(h * 64 + dd) * 9216 + b * 4608 + jj0 + k0;
            *(s16x8*)dst = o0;
            *(s16x8*)(dst + 8) = o1;
        }
    } else {
        // ---- weight transpose ----
        float (*st)[68] = (float(*)[68])smem;
        const int t2 = bid - 2432;
        const int k0 = (t2 & 7) * 64;
        const int nt = t2 >> 3;
        const int z  = nt >> 3;
        const int n0 = (nt & 7) * 64;
        const float* wz = (z == 0) ? wq : (z == 1) ? wk : wv;
        const float scale = (z == 0) ? 0.125f : 1.0f;
        {
            int kk = tid >> 4, nn = (tid & 15) * 4;
            #pragma unroll
            for (int it = 0; it < 4; ++it) {
                f32x4 x = *(const f32x4*)(wz + (size_t)(k0 + kk + it * 16) * 512 + n0 + nn);
                *(f32x4*)&st[kk + it * 16][nn] = x;
            }
        }
        __syncthreads();
        {
            int nn2 = tid >> 2, kseg = (tid & 3) * 16;
            s16x8 o0, o1;
            #pragma unroll
            for (int j = 0; j < 8; ++j) o0[j] = f2bf(st[kseg + j][nn2] * scale);
            #pragma unroll
            for (int j = 0; j < 8; ++j) o1[j] = f2bf(st[kseg + 8 + j][nn2] * scale);
            short* dst = wt + (size_t)(z * 512 + n0 + nn2) * 512 + k0 + kseg;
            *(s16x8*)(dst) = o0;
            *(s16x8*)(dst + 8) = o1;
        }
    }
}

// ---------------------------------------------------------------------------
// Fused QKV projection, BK=32 double-buffered async pipeline (prefetch dist 1).
// z=0/1 -> row-major bf16 q/k; z=2 -> transposed vbt.
// Epilogue also writes next_k/next_v (fp32).
// ---------------------------------------------------------------------------
__global__ __launch_bounds__(256, 4)
void proj_kernel(const short* __restrict__ xsbf, const short* __restrict__ wt,
                 short* __restrict__ qkbf, short* __restrict__ vbt,
                 float* __restrict__ out)
{
    __shared__ short Xs[2][128][32];   // [buf][row][k], 64B rows, swizzled granules
    __shared__ short Ws[2][128][32];

    const int tid = threadIdx.x;
    const int m0  = blockIdx.x * 128;
    const int n0  = blockIdx.y * 128;
    const int z   = n0 >> 9;
    const int ln0 = n0 & 511;
    const int wave = tid >> 6, lane = tid & 63;
    const int wq = (wave & 1) * 64;
    const int wx = (wave >> 1) * 64;
    const int lr = lane & 15, quad = lane >> 4;

    f32x4 acc[4][4] = {};

    const int r16 = lane >> 2;     // 0..15: row within 16-row group
    const int g4  = lane & 3;      // granule (16B) within 64B row

    // wave w stages rows [32w, 32w+32) of both tiles: 2 gl_lds16 each
    auto issue = [&](int k0, int pb) {
        #pragma unroll
        for (int i = 0; i < 2; ++i) {
            int row = 32 * wave + 16 * i + r16;
            int gs  = g4 ^ (row & 3);
            gl_lds16(xsbf + (size_t)(m0 + row) * 512 + k0 + gs * 8,
                     &Xs[pb][32 * wave + 16 * i][0]);
            gl_lds16(wt   + (size_t)(n0 + row) * 512 + k0 + gs * 8,
                     &Ws[pb][32 * wave + 16 * i][0]);
        }
    };

    issue(0, 0);

    for (int it = 0; it < 16; ++it) {
        const int pb = it & 1;
        drain_vmem();                 // loads for iter `it` were issued 1 iter ago
        __syncthreads();
        if (it < 15) issue(32 * (it + 1), pb ^ 1);   // overlaps compute below

        s16x8 af[4], bf[4];
        #pragma unroll
        for (int ta = 0; ta < 4; ++ta) {
            int R = wq + ta * 16 + lr;
            af[ta] = *(const s16x8*)&Ws[pb][R][((quad ^ (R & 3)) * 8)];
        }
        #pragma unroll
        for (int tb = 0; tb < 4; ++tb) {
            int R = wx + tb * 16 + lr;
            bf[tb] = *(const s16x8*)&Xs[pb][R][((quad ^ (R & 3)) * 8)];
        }
        #pragma unroll
        for (int ta = 0; ta < 4; ++ta)
            #pragma unroll
            for (int tb = 0; tb < 4; ++tb)
                acc[ta][tb] = __builtin_amdgcn_mfma_f32_16x16x32_bf16(
                    af[ta], bf[tb], acc[ta][tb], 0, 0, 0);
    }

    #pragma unroll
    for (int ta = 0; ta < 4; ++ta)
        #pragma unroll
        for (int tb = 0; tb < 4; ++tb) {
            int m  = m0 + wx + tb * 16 + lr;
            int ln = ln0 + wq + ta * 16 + quad * 4;
            int bb = m >> 12, seq = m & 4095;
            if (z < 2) {
                short* base = qkbf + (size_t)z * ((size_t)8192 * 512);
                s16x4 o;
                o[0] = f2bf(acc[ta][tb][0]); o[1] = f2bf(acc[ta][tb][1]);
                o[2] = f2bf(acc[ta][tb][2]); o[3] = f2bf(acc[ta][tb][3]);
                *(s16x4*)(base + (size_t)m * 512 + ln) = o;
                if (z == 1 && seq >= 3584) {
                    float* dst = out + 4194304 + ((size_t)(bb * 512 + seq - 3584)) * 512 + ln;
                    *(f32x4*)dst = acc[ta][tb];
                }
            } else {
                size_t col = (size_t)bb * 4608 + 512 + seq;
                #pragma unroll
                for (int g = 0; g < 4; ++g)
                    vbt[(size_t)(ln + g) * 9216 + col] = f2bf(acc[ta][tb][g]);
                if (seq >= 3584) {
                    float* dst = out + 4194304 + 524288 + ((size_t)(bb * 512 + seq - 3584)) * 512 + ln;
                    *(f32x4*)dst = acc[ta][tb];
                }
            }
        }
}

// ---------------------------------------------------------------------------
// MFMA flash attention, S^T formulation + fixed-max softmax + async staging.
// Block = (b, window n, head h, 128 q rows); 512 thr = 8 waves x 16 q rows.
// ---------------------------------------------------------------------------
__global__ __launch_bounds__(512, 4)
void attn_kernel(const short* __restrict__ qkbf, const short* __restrict__ vbt,
                 const short* __restrict__ pkbf, const float* __restrict__ rel_bias,
                 float* __restrict__ out)
{
    __shared__ short k_s[2][64][64];     // [buf][key][d], XOR-swizzled granules
    __shared__ short vt_s[2][64][64];    // [buf][d][key], XOR-swizzled granules
    __shared__ short p_s[128][64];       // per-wave P rows, XOR-swizzled
    __shared__ float bias_s[512];

    const short* qb = qkbf;
    const short* kb = qkbf + (size_t)8192 * 512;

    const int bid = blockIdx.x;
    const int qt = bid & 3;
    const int h  = (bid >> 2) & 7;
    const int n  = (bid >> 5) & 7;
    const int b  = bid >> 8;
    const int tid = threadIdx.x;
    const int wave = tid >> 6, lane = tid & 63;
    const int lr = lane & 15, quad = lane >> 4;
    const int q0 = qt * 128;
    const int i0 = q0 + 16 * wave;

    // T5 bias table (512 entries, one per thread)
    {
        int nd = tid;
        int bucket;
        if (nd < 16) bucket = nd;
        else {
            int vbk = 16 + (int)(log((double)nd * (1.0 / 16.0)) * (16.0 / log(8.0)));
            bucket = vbk < 31 ? vbk : 31;
        }
        bias_s[nd] = rel_bias[h * 32 + bucket];
    }
    const float bias31 = rel_bias[h * 32 + 31];

    // Q B-frag direct from global
    s16x8 aq[2];
    {
        const short* src = qb + (size_t)(b * S_ + n * W_ + i0 + lr) * 512 + h * 64 + quad * 8;
        aq[0] = *(const s16x8*)(src);
        aq[1] = *(const s16x8*)(src + 32);
    }

    f32x4 oacc[4] = {};
    float lsum = 0.f;

    const int cmin = (16 * wave) >> 6;
    const int cmax = (16 * wave + 527) >> 6;

    const int r8 = lane >> 3, gr = lane & 7;

    // async staging: wave w stages rows 8w..8w+7 of K chunk and of V^T chunk
    // keys for chunk c are jj in [q0 + 64c, q0 + 64c + 64)  (window coords)
    auto issueKV = [&](int c, int pb) {
        int jj = q0 + 64 * c + 8 * wave + r8;          // key in [q0, q0+640)
        int p  = n * W_ + jj - W_;
        int gs = gr ^ r8;
        const short* ksrc = (p >= 0)
            ? kb   + ((size_t)(b * S_ + p)) * 512 + h * 64 + gs * 8
            : pkbf + (((size_t)(b * W_ + jj)) * 8 + h) * 64 + gs * 8;
        gl_lds16(ksrc, &k_s[pb][8 * wave][0]);
        int drow = 8 * wave + r8;
        const short* vsrc = vbt + (size_t)(h * 64 + drow) * 9216
                          + b * 4608 + n * W_ + q0 + 64 * c + gs * 8;
        gl_lds16(vsrc, &vt_s[pb][8 * wave][0]);
    };

    issueKV(0, 0);

    for (int c = 0; c < 10; ++c) {
        const int pb = c & 1;
        drain_vmem();                    // our async writes land BEFORE barrier
        __syncthreads();                 // now all waves' chunk-c rows are valid
        if (c < 9) issueKV(c + 1, pb ^ 1);   // overlaps compute below
        if (c < cmin || c > cmax) continue;

        // ---- S^T = K * Q^T : D[key][q], col=lane&15=q, row=quad*4+rg=key ----
        f32x4 sacc[4] = {};
        #pragma unroll
        for (int ks = 0; ks < 2; ++ks) {
            s16x8 bk[4];
            #pragma unroll
            for (int tn = 0; tn < 4; ++tn)
                bk[tn] = *(const s16x8*)&k_s[pb][tn * 16 + lr][(((4 * ks + quad) ^ (lr & 7)) * 8)];
            #pragma unroll
            for (int tn = 0; tn < 4; ++tn)
                sacc[tn] = __builtin_amdgcn_mfma_f32_16x16x32_bf16(
                    bk[tn], aq[ks], sacc[tn], 0, 0, 0);
        }

        // ---- bias + mask + exp (no running max needed) ----
        const int ib = i0 + lr;          // this lane's q row (window coords)
        const int jb = q0 + 64 * c;
        if (64 * c - 16 * wave <= 336) {
            // all valid pairs have nd >= 113 -> bucket 31 (constant bias)
            #pragma unroll
            for (int tn = 0; tn < 4; ++tn) {
                s16x4 pp;
                #pragma unroll
                for (int rg = 0; rg < 4; ++rg) {
                    int j = jb + tn * 16 + quad * 4 + rg;
                    unsigned dm1 = (unsigned)(j - ib - 1);
                    float sv = (dm1 < 512u) ? (sacc[tn][rg] + bias31) : MASKV;
                    float p = __expf(sv);
                    lsum += p;
                    pp[rg] = f2bf(p);
                }
                int gp = (2 * tn + (quad >> 1)) ^ (lr & 7);
                *(s16x4*)&p_s[16 * wave + lr][gp * 8 + (quad & 1) * 4] = pp;
            }
        } else {
            #pragma unroll
            for (int tn = 0; tn < 4; ++tn) {
                s16x4 pp;
                #pragma unroll
                for (int rg = 0; rg < 4; ++rg) {
                    int j = jb + tn * 16 + quad * 4 + rg;
                    unsigned dm1 = (unsigned)(j - ib - 1);
                    float bias = bias_s[(ib + 512 - j) & 511];
                    float sv = (dm1 < 512u) ? (sacc[tn][rg] + bias) : MASKV;
                    float p = __expf(sv);
                    lsum += p;
                    pp[rg] = f2bf(p);
                }
                int gp = (2 * tn + (quad >> 1)) ^ (lr & 7);
                *(s16x4*)&p_s[16 * wave + lr][gp * 8 + (quad & 1) * 4] = pp;
            }
        }

        asm volatile("s_waitcnt lgkmcnt(0)" ::: "memory");

        // ---- O += P V : A=P (q x keys), B=V (keys x d) ----
        #pragma unroll
        for (int ks = 0; ks < 2; ++ks) {
            int gpa = (4 * ks + quad) ^ (lr & 7);
            s16x8 ap = *(const s16x8*)&p_s[16 * wave + lr][gpa * 8];
            s16x8 bv[4];
            #pragma unroll
            for (int tn = 0; tn < 4; ++tn)
                bv[tn] = *(const s16x8*)&vt_s[pb][tn * 16 + lr][(((4 * ks + quad) ^ (lr & 7)) * 8)];
            #pragma unroll
            for (int tn = 0; tn < 4; ++tn)
                oacc[tn] = __builtin_amdgcn_mfma_f32_16x16x32_bf16(
                    ap, bv[tn], oacc[tn], 0, 0, 0);
        }
    }

    // ---- final l reduction over quads; redistribute; store ----
    lsum += __shfl_xor(lsum, 16);
    lsum += __shfl_xor(lsum, 32);
    float linv[4];
    #pragma unroll
    for (int rg = 0; rg < 4; ++rg)
        linv[rg] = 1.0f / __shfl(lsum, quad * 4 + rg);

    #pragma unroll
    for (int rg = 0; rg < 4; ++rg) {
        int row = i0 + quad * 4 + rg;
        float* dst = out + (((size_t)b * S_ + n * W_ + row) * H_ + h) * D_ + lr;
        #pragma unroll
        for (int tn = 0; tn < 4; ++tn)
            dst[tn * 16] = oacc[tn][rg] * linv[rg];
    }
}

extern "C" void kernel_launch(void* const* d_in, const int* in_sizes, int n_in,
                              void* d_out, int out_size, void* d_ws, size_t ws_size,
                              hipStream_t stream)
{
    const float* xs       = (const float*)d_in[0];
    const float* prev_k   = (const float*)d_in[1];
    const float* prev_v   = (const float*)d_in[2];
    const float* w_q      = (const float*)d_in[3];
    const float* w_k      = (const float*)d_in[4];
    const float* w_v      = (const float*)d_in[5];
    const float* rel_bias = (const float*)d_in[6];
    float* out = (float*)d_out;

    short* xsbf = (short*)d_ws;                         // 4,194,304
    short* wt   = xsbf + (size_t)4194304;               //   786,432
    short* qkbf = wt   + (size_t)786432;                // 8,388,608 (q then k)
    short* pkbf = qkbf + (size_t)8388608;               //   524,288
    short* vbt  = pkbf + (size_t)524288;                // 512 x 9216

    prep_kernel<<<2624, 256, 0, stream>>>(xs, prev_k, prev_v, w_q, w_k, w_v,
                                          xsbf, pkbf, vbt, wt);

    proj_kernel<<<dim3(64, 12), 256, 0, stream>>>(xsbf, wt, qkbf, vbt, out);

    attn_kernel<<<512, 512, 0, stream>>>(qkbf, vbt, pkbf, rel_bias, out);
}